// Round 3
// baseline (465.605 us; speedup 1.0000x reference)
//
#include <hip/hip_runtime.h>
#include <hip/hip_bf16.h>
#include <cstdint>
#include <cstddef>

#define B_ 2
#define T_ 6
#define P_ 10000
#define DIMM 128
#define DSTAT 16
#define G0_ 3
#define G1_ 10
#define NTOK (B_*T_*P_)   /* 120000 */
#define NWIN 4000
#define LWIN 30

typedef __attribute__((ext_vector_type(8))) short short8;
typedef __attribute__((ext_vector_type(4))) float f32x4;

__device__ __forceinline__ float frcp_(float x){ return __builtin_amdgcn_rcpf(x); }
__device__ __forceinline__ float fsilu_(float x){ return x*frcp_(1.f+__expf(-x)); }
__device__ __forceinline__ float fsoftplus_(float x){ return (x>15.f)? x : __logf(1.f+__expf(x)); }
__device__ __forceinline__ float geluf_(float x){ return 0.5f*x*(1.f+erff(x*0.70710678118654752f)); }

__device__ __forceinline__ unsigned short bf16bits_(float x){
  __hip_bfloat16 h = __float2bfloat16(x);
  union { __hip_bfloat16 h; unsigned short u; } cv; cv.h = h; return cv.u;
}
__device__ __forceinline__ float bits2f_(unsigned short u){
  union { unsigned u; float f; } cv; cv.u = ((unsigned)u)<<16; return cv.f;
}

// ---------------- weight conversion + W_delta fold ----------------
// wbuf (bf16 elems): [0,32768) ipw; [32768,49152) opw; [49152,65536) f1w;
// [65536,81920) f2w; [81920,118784) Wbig[2][144][128]
__global__ __launch_bounds__(256) void k_cvt(
    const float* __restrict__ ipw, const float* __restrict__ opw,
    const float* __restrict__ f1w, const float* __restrict__ f2w,
    const float* __restrict__ xpw, const float* __restrict__ dtw,
    __hip_bfloat16* __restrict__ wbuf)
{
  int i = blockIdx.x*256 + threadIdx.x;
  if (i >= 118784) return;
  float v;
  if (i < 32768) v = ipw[i];
  else if (i < 49152) v = opw[i - 32768];
  else if (i < 65536) v = f1w[i - 49152];
  else if (i < 81920) v = f2w[i - 65536];
  else {
    int j = i - 81920;
    int d = j / 18432;
    int rr = (j >> 7) % 144;
    int k = j & 127;
    if (rr < 128) {
      v = 0.f;
      #pragma unroll
      for (int r=0;r<8;r++) v += dtw[(d*128+rr)*8+r]*xpw[(d*10+r)*128+k];
    } else if (rr == 128) v = xpw[(d*10+8)*128+k];
    else if (rr == 129)  v = xpw[(d*10+9)*128+k];
    else v = 0.f;
  }
  wbuf[i] = __float2bfloat16(v);
}

// ---------------- prep: gather + LN + loan1 -> hpre bf16, wave per token ----------------
__global__ __launch_bounds__(256) void k_prep(
    const float* __restrict__ x, const float* __restrict__ xst,
    const int* __restrict__ curves,
    const float* __restrict__ l1w, const float* __restrict__ l1b,
    __hip_bfloat16* __restrict__ hpre)
{
  int token = blockIdx.x*4 + (threadIdx.x>>6);
  int lane = threadIdx.x & 63;
  int b = token/60000, rem = token%60000, t = rem/10000, i = rem%10000;
  int c0 = curves[b*2*P_ + i];
  size_t src = ((size_t)(b*T_+t))*P_ + c0;
  float2 v = *reinterpret_cast<const float2*>(&x[src*128 + lane*2]);
  float s = v.x+v.y, q = v.x*v.x+v.y*v.y;
  #pragma unroll
  for (int d=1;d<64;d<<=1){ s += __shfl_xor(s,d); q += __shfl_xor(q,d); }
  float m = s*(1.f/128.f), var = q*(1.f/128.f)-m*m, rs = rsqrtf(var+1e-5f);
  float sv = (lane<16)? xst[src*16+lane] : 0.f;
  int c = lane*2;
  float a0 = l1b[c], a1 = l1b[c+1];
  #pragma unroll
  for (int j=0;j<16;j++){
    float sj = __shfl(sv, j);
    a0 += sj*l1w[c*16+j];
    a1 += sj*l1w[(c+1)*16+j];
  }
  __hip_bfloat162 o;
  o.x = __float2bfloat16((v.x-m)*rs + a0);
  o.y = __float2bfloat16((v.y-m)*rs + a1);
  *reinterpret_cast<__hip_bfloat162*>(&hpre[(size_t)token*128 + c]) = o;
}

// ---------------- in_proj GEMM: Hbf[M,256] = hpre[M,128] @ ipw[256,128]^T ----------------
__global__ __launch_bounds__(256) void k_gemm_in(
    const __hip_bfloat16* __restrict__ A, const __hip_bfloat16* __restrict__ Wb,
    __hip_bfloat16* __restrict__ C)
{
  __shared__ __hip_bfloat16 As[96][136];
  __shared__ __hip_bfloat16 Bs[128][136];
  const int tid = threadIdx.x;
  const size_t m0 = (size_t)blockIdx.x * 96;
  const int n0 = blockIdx.y * 128;
  #pragma unroll
  for (int p = 0; p < 6; ++p) {
    int ch = tid + p*256; int r = ch >> 4, c16 = ch & 15;
    *reinterpret_cast<uint4*>(&As[r][c16*8]) =
      *reinterpret_cast<const uint4*>(&A[(m0 + r)*128 + c16*8]);
  }
  #pragma unroll
  for (int p = 0; p < 8; ++p) {
    int ch = tid + p*256; int r = ch >> 4, c16 = ch & 15;
    *reinterpret_cast<uint4*>(&Bs[r][c16*8]) =
      *reinterpret_cast<const uint4*>(&Wb[(size_t)(n0 + r)*128 + c16*8]);
  }
  __syncthreads();
  const int wave = tid >> 6, lane = tid & 63;
  const int rb = (wave >> 1) * 48, cb = (wave & 1) * 64;
  const int lrow = lane & 15, koff = (lane >> 4) * 8;
  f32x4 acc[3][4];
  #pragma unroll
  for (int i=0;i<3;i++) for (int j=0;j<4;j++) acc[i][j] = f32x4{0.f,0.f,0.f,0.f};
  #pragma unroll
  for (int kb = 0; kb < 4; ++kb) {
    short8 a[3], bf[4];
    #pragma unroll
    for (int i=0;i<3;i++) a[i] = *reinterpret_cast<const short8*>(&As[rb + i*16 + lrow][kb*32 + koff]);
    #pragma unroll
    for (int j=0;j<4;j++) bf[j] = *reinterpret_cast<const short8*>(&Bs[cb + j*16 + lrow][kb*32 + koff]);
    #pragma unroll
    for (int i=0;i<3;i++)
      #pragma unroll
      for (int j=0;j<4;j++)
        acc[i][j] = __builtin_amdgcn_mfma_f32_16x16x32_bf16(a[i], bf[j], acc[i][j], 0,0,0);
  }
  const int crow0 = (lane >> 4) * 4, ccol = lane & 15;
  #pragma unroll
  for (int i=0;i<3;i++) for (int j=0;j<4;j++){
    int n = n0 + cb + j*16 + ccol;
    #pragma unroll
    for (int r=0;r<4;r++){
      size_t m = m0 + rb + i*16 + crow0 + r;
      C[m*256 + n] = __float2bfloat16(acc[i][j][r]);
    }
  }
}

// ---------------- fused conv + xproj(MFMA, dt folded) + scan ----------------
__global__ __launch_bounds__(128) void k_scan(
    const __hip_bfloat16* __restrict__ H,
    const float* __restrict__ conv_w, const float* __restrict__ conv_b,
    const __hip_bfloat16* __restrict__ Wbig,   // [2][144][128]
    const float* __restrict__ dt_b, const float* __restrict__ A_log,
    const float* __restrict__ Dp,
    __hip_bfloat16* __restrict__ Y)
{
  const int bid = blockIdx.x;
  const int dir = bid / NWIN;
  const int n   = bid % NWIN;
  const int c = threadIdx.x;
  const int b  = n / 2000;
  const int a  = (n / 1000) & 1;
  const int qw = n % 1000;
  __shared__ __hip_bfloat16 u_bf[32][136];
  __shared__ unsigned es[32][132];
  __shared__ float Bs_[32], Cs_[32];

  const int row0 = (b*T_ + a*G0_)*P_;
  float u[LWIN], z[LWIN];
  {
    float w0 = conv_w[(dir*DIMM + c)*3 + 0];
    float w1 = conv_w[(dir*DIMM + c)*3 + 1];
    float w2 = conv_w[(dir*DIMM + c)*3 + 2];
    float cbv = conv_b[dir*DIMM + c];
    float xm1 = 0.f, xm2 = 0.f;
    #pragma unroll
    for (int l=0;l<LWIN;l++){
      int pf = qw*G1_ + l%G1_;
      int p  = dir ? (P_-1-pf) : pf;
      size_t base = ((size_t)(row0 + (l/G1_)*P_ + p))*256;
      float xc = __bfloat162float(H[base + c]);
      z[l] = __bfloat162float(H[base + 128 + c]);
      u[l] = fsilu_(w0*xm2 + w1*xm1 + w2*xc + cbv);
      xm2 = xm1; xm1 = xc;
    }
  }
  #pragma unroll
  for (int l=0;l<LWIN;l++) u_bf[l][c] = __float2bfloat16(u[l]);
  u_bf[30][c] = __float2bfloat16(0.f);
  u_bf[31][c] = __float2bfloat16(0.f);
  __syncthreads();

  {
    const int wave = c >> 6, lane = c & 63;
    const int lrow = lane & 15, koff = (lane >> 4) * 8;
    const __hip_bfloat16* Wd = Wbig + (size_t)dir*144*128;
    f32x4 acc[9];
    #pragma unroll
    for (int t=0;t<9;t++) acc[t] = f32x4{0.f,0.f,0.f,0.f};
    #pragma unroll
    for (int kb=0; kb<4; ++kb){
      short8 av = *reinterpret_cast<const short8*>(&u_bf[wave*16 + lrow][kb*32 + koff]);
      #pragma unroll
      for (int t=0;t<9;t++){
        short8 bv = *reinterpret_cast<const short8*>(&Wd[(size_t)(t*16 + lrow)*128 + kb*32 + koff]);
        acc[t] = __builtin_amdgcn_mfma_f32_16x16x32_bf16(av, bv, acc[t], 0,0,0);
      }
    }
    const int l0 = wave*16 + (lane>>4)*4;
    #pragma unroll
    for (int t=0;t<8;t++){
      int j = t*16 + lrow;
      float dtbj = dt_b[dir*128 + j];
      float Avj = -__expf(A_log[dir*128 + j]);
      #pragma unroll
      for (int r=0;r<4;r++){
        float d = fsoftplus_(acc[t][r] + dtbj);
        float dA = __expf(d*Avj);
        es[l0+r][j] = (((unsigned)bf16bits_(dA))<<16) | (unsigned)bf16bits_(d);
      }
    }
    if (lrow < 2){
      #pragma unroll
      for (int r=0;r<4;r++){
        if (lrow==0) Bs_[l0+r] = acc[8][r];
        else         Cs_[l0+r] = acc[8][r];
      }
    }
  }
  __syncthreads();

  float Dv = Dp[dir*DIMM + c];
  float hst = 0.f;
  __hip_bfloat16* Yp = Y + ((size_t)dir*NWIN + n)*LWIN*DIMM;
  #pragma unroll
  for (int l=0;l<LWIN;l++){
    unsigned pk = es[l][c];
    float dA  = bits2f_((unsigned short)(pk>>16));
    float dlt = bits2f_((unsigned short)(pk & 0xffffu));
    float term = dlt*u[l]*Bs_[l];
    hst = fmaf(dA, hst, term);
    float y = fmaf(hst, Cs_[l], u[l]*Dv);
    y *= fsilu_(z[l]);
    Yp[l*DIMM + c] = __float2bfloat16(y);
  }
}

// ---------------- _wrev scramble index ----------------
__device__ __forceinline__ int win_index(int t, int p){
  int G  = t*P_ + p;
  int d3 = G / 6000;
  int r  = G % 6000;
  int d1 = r / 6;
  int r2 = r % 6;
  int d4 = r2 >> 1;
  int d2 = r2 & 1;
  int F  = d1*60 + d2*30 + d3*3 + d4;
  int a  = F / 30000;
  int F2 = F % 30000;
  int qw = F2 / 30;
  int l  = F2 % 30;
  return (a*1000 + qw)*LWIN + l;
}

// ---------------- out_proj GEMM with fused gather/average A-load ----------------
__global__ __launch_bounds__(256) void k_gemm_out(
    const __hip_bfloat16* __restrict__ Y, const __hip_bfloat16* __restrict__ Wb,
    float* __restrict__ yproj)
{
  __shared__ __hip_bfloat16 As[96][136];
  __shared__ __hip_bfloat16 Bs[128][136];
  const int tid = threadIdx.x;
  const size_t m0 = (size_t)blockIdx.x * 96;
  const __hip_bfloat16* Yb = Y + (size_t)NWIN*LWIN*DIMM;
  #pragma unroll
  for (int p = 0; p < 6; ++p) {
    int ch = tid + p*256; int r = ch >> 4, c16 = ch & 15;
    int token = (int)m0 + r;
    int b = token/60000, rem = token%60000, t = rem/10000, pp = rem%10000;
    size_t bbase = (size_t)b*60000;
    int wf = win_index(t, pp), wb = win_index(t, P_-1-pp);
    uint4 f = *reinterpret_cast<const uint4*>(&Y [(bbase+wf)*128 + c16*8]);
    uint4 g = *reinterpret_cast<const uint4*>(&Yb[(bbase+wb)*128 + c16*8]);
    unsigned o[4];
    const unsigned* fu = reinterpret_cast<const unsigned*>(&f);
    const unsigned* gu = reinterpret_cast<const unsigned*>(&g);
    #pragma unroll
    for (int k=0;k<4;k++){
      float flo = bits2f_((unsigned short)(fu[k] & 0xffffu));
      float fhi = bits2f_((unsigned short)(fu[k] >> 16));
      float glo = bits2f_((unsigned short)(gu[k] & 0xffffu));
      float ghi = bits2f_((unsigned short)(gu[k] >> 16));
      o[k] = (((unsigned)bf16bits_(0.5f*(fhi+ghi)))<<16) | (unsigned)bf16bits_(0.5f*(flo+glo));
    }
    *reinterpret_cast<uint4*>(&As[r][c16*8]) = *reinterpret_cast<uint4*>(o);
  }
  #pragma unroll
  for (int p = 0; p < 8; ++p) {
    int ch = tid + p*256; int r = ch >> 4, c16 = ch & 15;
    *reinterpret_cast<uint4*>(&Bs[r][c16*8]) =
      *reinterpret_cast<const uint4*>(&Wb[(size_t)r*128 + c16*8]);
  }
  __syncthreads();
  const int wave = tid >> 6, lane = tid & 63;
  const int rb = (wave >> 1) * 48, cb = (wave & 1) * 64;
  const int lrow = lane & 15, koff = (lane >> 4) * 8;
  f32x4 acc[3][4];
  #pragma unroll
  for (int i=0;i<3;i++) for (int j=0;j<4;j++) acc[i][j] = f32x4{0.f,0.f,0.f,0.f};
  #pragma unroll
  for (int kb = 0; kb < 4; ++kb) {
    short8 a[3], bf[4];
    #pragma unroll
    for (int i=0;i<3;i++) a[i] = *reinterpret_cast<const short8*>(&As[rb + i*16 + lrow][kb*32 + koff]);
    #pragma unroll
    for (int j=0;j<4;j++) bf[j] = *reinterpret_cast<const short8*>(&Bs[cb + j*16 + lrow][kb*32 + koff]);
    #pragma unroll
    for (int i=0;i<3;i++)
      #pragma unroll
      for (int j=0;j<4;j++)
        acc[i][j] = __builtin_amdgcn_mfma_f32_16x16x32_bf16(a[i], bf[j], acc[i][j], 0,0,0);
  }
  const int crow0 = (lane >> 4) * 4, ccol = lane & 15;
  #pragma unroll
  for (int i=0;i<3;i++) for (int j=0;j<4;j++){
    int nn = cb + j*16 + ccol;
    #pragma unroll
    for (int r=0;r<4;r++){
      size_t m = m0 + rb + i*16 + crow0 + r;
      yproj[m*128 + nn] = acc[i][j][r];
    }
  }
}

// ---------------- mid: x1 = xs + yproj ; gmid = LN(x1) + loan2, wave per token ----------------
__global__ __launch_bounds__(256) void k_mid(
    const float* __restrict__ x, const float* __restrict__ xst,
    const int* __restrict__ curves, const float* __restrict__ yproj,
    const float* __restrict__ l2w, const float* __restrict__ l2b,
    float* __restrict__ x1, __hip_bfloat16* __restrict__ gmid)
{
  int token = blockIdx.x*4 + (threadIdx.x>>6);
  int lane = threadIdx.x & 63;
  int b = token/60000, rem = token%60000, t = rem/10000, i = rem%10000;
  int c0 = curves[b*2*P_ + i];
  size_t src = ((size_t)(b*T_+t))*P_ + c0;
  int c = lane*2;
  float2 v = *reinterpret_cast<const float2*>(&x[src*128 + c]);
  float2 yp = *reinterpret_cast<const float2*>(&yproj[(size_t)token*128 + c]);
  v.x += yp.x; v.y += yp.y;
  *reinterpret_cast<float2*>(&x1[(size_t)token*128 + c]) = v;
  float s = v.x+v.y, q = v.x*v.x+v.y*v.y;
  #pragma unroll
  for (int d=1;d<64;d<<=1){ s += __shfl_xor(s,d); q += __shfl_xor(q,d); }
  float m = s*(1.f/128.f), var = q*(1.f/128.f)-m*m, rs = rsqrtf(var+1e-5f);
  float sv = (lane<16)? xst[src*16+lane] : 0.f;
  float a0 = l2b[c], a1 = l2b[c+1];
  #pragma unroll
  for (int j=0;j<16;j++){
    float sj = __shfl(sv, j);
    a0 += sj*l2w[c*16+j];
    a1 += sj*l2w[(c+1)*16+j];
  }
  __hip_bfloat162 o;
  o.x = __float2bfloat16((v.x-m)*rs + a0);
  o.y = __float2bfloat16((v.y-m)*rs + a1);
  *reinterpret_cast<__hip_bfloat162*>(&gmid[(size_t)token*128 + c]) = o;
}

// ---------------- fused MLP: x2 = x1 + fc2(gelu(fc1(gmid))) ----------------
__global__ __launch_bounds__(256) void k_gemm_mlp(
    const __hip_bfloat16* __restrict__ A, const __hip_bfloat16* __restrict__ W1,
    const __hip_bfloat16* __restrict__ W2,
    const float* __restrict__ b1, const float* __restrict__ b2,
    const float* __restrict__ x1, float* __restrict__ x2)
{
  __shared__ __hip_bfloat16 As[96][136];
  __shared__ __hip_bfloat16 Bs[128][136];
  const int tid = threadIdx.x;
  const size_t m0 = (size_t)blockIdx.x * 96;
  #pragma unroll
  for (int p = 0; p < 6; ++p) {
    int ch = tid + p*256; int r = ch >> 4, c16 = ch & 15;
    *reinterpret_cast<uint4*>(&As[r][c16*8]) =
      *reinterpret_cast<const uint4*>(&A[(m0 + r)*128 + c16*8]);
  }
  #pragma unroll
  for (int p = 0; p < 8; ++p) {
    int ch = tid + p*256; int r = ch >> 4, c16 = ch & 15;
    *reinterpret_cast<uint4*>(&Bs[r][c16*8]) =
      *reinterpret_cast<const uint4*>(&W1[(size_t)r*128 + c16*8]);
  }
  __syncthreads();
  const int wave = tid >> 6, lane = tid & 63;
  const int rb = (wave >> 1) * 48, cb = (wave & 1) * 64;
  const int lrow = lane & 15, koff = (lane >> 4) * 8;
  const int crow0 = (lane >> 4) * 4, ccol = lane & 15;
  f32x4 acc[3][4];
  #pragma unroll
  for (int i=0;i<3;i++) for (int j=0;j<4;j++) acc[i][j] = f32x4{0.f,0.f,0.f,0.f};
  #pragma unroll
  for (int kb = 0; kb < 4; ++kb) {
    short8 a[3], bf[4];
    #pragma unroll
    for (int i=0;i<3;i++) a[i] = *reinterpret_cast<const short8*>(&As[rb + i*16 + lrow][kb*32 + koff]);
    #pragma unroll
    for (int j=0;j<4;j++) bf[j] = *reinterpret_cast<const short8*>(&Bs[cb + j*16 + lrow][kb*32 + koff]);
    #pragma unroll
    for (int i=0;i<3;i++)
      #pragma unroll
      for (int j=0;j<4;j++)
        acc[i][j] = __builtin_amdgcn_mfma_f32_16x16x32_bf16(a[i], bf[j], acc[i][j], 0,0,0);
  }
  __syncthreads();   // all reads of As/Bs done
  // write gelu(a1) into As; reload Bs with W2
  #pragma unroll
  for (int i=0;i<3;i++) for (int j=0;j<4;j++){
    int nn = cb + j*16 + ccol;
    float bv = b1[nn];
    #pragma unroll
    for (int r=0;r<4;r++){
      int row = rb + i*16 + crow0 + r;
      As[row][nn] = __float2bfloat16(geluf_(acc[i][j][r] + bv));
    }
  }
  #pragma unroll
  for (int p = 0; p < 8; ++p) {
    int ch = tid + p*256; int r = ch >> 4, c16 = ch & 15;
    *reinterpret_cast<uint4*>(&Bs[r][c16*8]) =
      *reinterpret_cast<const uint4*>(&W2[(size_t)r*128 + c16*8]);
  }
  __syncthreads();
  #pragma unroll
  for (int i=0;i<3;i++) for (int j=0;j<4;j++) acc[i][j] = f32x4{0.f,0.f,0.f,0.f};
  #pragma unroll
  for (int kb = 0; kb < 4; ++kb) {
    short8 a[3], bf[4];
    #pragma unroll
    for (int i=0;i<3;i++) a[i] = *reinterpret_cast<const short8*>(&As[rb + i*16 + lrow][kb*32 + koff]);
    #pragma unroll
    for (int j=0;j<4;j++) bf[j] = *reinterpret_cast<const short8*>(&Bs[cb + j*16 + lrow][kb*32 + koff]);
    #pragma unroll
    for (int i=0;i<3;i++)
      #pragma unroll
      for (int j=0;j<4;j++)
        acc[i][j] = __builtin_amdgcn_mfma_f32_16x16x32_bf16(a[i], bf[j], acc[i][j], 0,0,0);
  }
  #pragma unroll
  for (int i=0;i<3;i++) for (int j=0;j<4;j++){
    int nn = cb + j*16 + ccol;
    float bv = b2[nn];
    #pragma unroll
    for (int r=0;r<4;r++){
      size_t m = m0 + rb + i*16 + crow0 + r;
      x2[m*128 + nn] = acc[i][j][r] + bv + x1[m*128 + nn];
    }
  }
}

// ---------------- final: gather x2 by c1 ----------------
__global__ __launch_bounds__(256) void k_final(
    const float* __restrict__ x2, const int* __restrict__ curves,
    float* __restrict__ out)
{
  int token = blockIdx.x*4 + (threadIdx.x>>6);
  int lane = threadIdx.x & 63;
  int b = token/60000, rem = token%60000, t = rem/10000, i = rem%10000;
  int c1 = curves[(b*2+1)*P_ + i];
  size_t src = ((size_t)(b*T_+t))*P_ + c1;
  float2 v = *reinterpret_cast<const float2*>(&x2[src*128 + lane*2]);
  *reinterpret_cast<float2*>(&out[(size_t)token*128 + lane*2]) = v;
}

extern "C" void kernel_launch(void* const* d_in, const int* in_sizes, int n_in,
                              void* d_out, int out_size, void* d_ws, size_t ws_size,
                              hipStream_t stream) {
  const float* x        = (const float*)d_in[0];
  const float* xst      = (const float*)d_in[1];
  const int*   curves   = (const int*)  d_in[2];
  const float* loan1_w  = (const float*)d_in[3];
  const float* loan1_b  = (const float*)d_in[4];
  const float* loan2_w  = (const float*)d_in[5];
  const float* loan2_b  = (const float*)d_in[6];
  const float* in_proj_w  = (const float*)d_in[7];
  const float* out_proj_w = (const float*)d_in[8];
  const float* conv_w   = (const float*)d_in[9];
  const float* conv_b   = (const float*)d_in[10];
  const float* xproj_w  = (const float*)d_in[11];
  const float* dt_w     = (const float*)d_in[12];
  const float* dt_b     = (const float*)d_in[13];
  const float* A_log    = (const float*)d_in[14];
  const float* Dvec     = (const float*)d_in[15];
  const float* fc1_w    = (const float*)d_in[16];
  const float* fc1_b    = (const float*)d_in[17];
  const float* fc2_w    = (const float*)d_in[18];
  const float* fc2_b    = (const float*)d_in[19];
  float* out = (float*)d_out;

  char* ws = (char*)d_ws;
  // A [0,61.44MB): hpre -> Y -> gmid
  // B [61.44,122.88MB): Hbf -> x1
  // C [122.88,184.32MB): yproj -> x2
  // D [184.32MB,+232KB): bf16 weights
  const size_t RB = 61440000, RC = 122880000, RD = 184320000;
  __hip_bfloat16* hpre = (__hip_bfloat16*)(ws + 0);
  __hip_bfloat16* Ybuf = (__hip_bfloat16*)(ws + 0);
  __hip_bfloat16* gmid = (__hip_bfloat16*)(ws + 0);
  __hip_bfloat16* Hbf  = (__hip_bfloat16*)(ws + RB);
  float*          x1   = (float*)(ws + RB);
  float*          yproj= (float*)(ws + RC);
  float*          x2   = (float*)(ws + RC);
  __hip_bfloat16* wbuf = (__hip_bfloat16*)(ws + RD);
  __hip_bfloat16* ipw_bf = wbuf;
  __hip_bfloat16* opw_bf = wbuf + 32768;
  __hip_bfloat16* f1w_bf = wbuf + 49152;
  __hip_bfloat16* f2w_bf = wbuf + 65536;
  __hip_bfloat16* Wbig   = wbuf + 81920;

  k_cvt<<<464, 256, 0, stream>>>(in_proj_w, out_proj_w, fc1_w, fc2_w, xproj_w, dt_w, wbuf);
  k_prep<<<NTOK/4, 256, 0, stream>>>(x, xst, curves, loan1_w, loan1_b, hpre);

  dim3 g1(NTOK/96, 2);
  k_gemm_in<<<g1, 256, 0, stream>>>(hpre, ipw_bf, Hbf);

  k_scan<<<2*NWIN, 128, 0, stream>>>(Hbf, conv_w, conv_b, Wbig, dt_b, A_log, Dvec, Ybuf);

  k_gemm_out<<<NTOK/96, 256, 0, stream>>>(Ybuf, opw_bf, yproj);

  k_mid<<<NTOK/4, 256, 0, stream>>>(x, xst, curves, yproj, loan2_w, loan2_b, x1, gmid);

  k_gemm_mlp<<<NTOK/96, 256, 0, stream>>>(gmid, f1w_bf, f2w_bf, fc1_b, fc2_b, x1, x2);

  k_final<<<NTOK/4, 256, 0, stream>>>(x2, curves, out);
}

// Round 4
// 289.735 us; speedup vs baseline: 1.6070x; 1.6070x over previous
//
#include <hip/hip_runtime.h>
#include <hip/hip_bf16.h>
#include <cstdint>
#include <cstddef>

#define B_ 2
#define T_ 6
#define P_ 10000
#define DIMM 128
#define DSTAT 16
#define G0_ 3
#define G1_ 10
#define NTOK (B_*T_*P_)   /* 120000 */
#define NWIN 4000
#define LWIN 30
#define KEXT 160          /* 128 + 16 static + 16 zero pad */

typedef __attribute__((ext_vector_type(8))) short short8;
typedef __attribute__((ext_vector_type(4))) float f32x4;

__device__ __forceinline__ float frcp_(float x){ return __builtin_amdgcn_rcpf(x); }
__device__ __forceinline__ float fsilu_(float x){ return x*frcp_(1.f+__expf(-x)); }
__device__ __forceinline__ float fsoftplus_(float x){ return (x>15.f)? x : __logf(1.f+__expf(x)); }
__device__ __forceinline__ float geluf_(float x){ return 0.5f*x*(1.f+erff(x*0.70710678118654752f)); }

__device__ __forceinline__ unsigned short bf16bits_(float x){
  union { __hip_bfloat16 h; unsigned short u; } cv; cv.h = __float2bfloat16(x); return cv.u;
}
__device__ __forceinline__ float bits2f_(unsigned short u){
  union { unsigned u; float f; } cv; cv.u = ((unsigned)u)<<16; return cv.f;
}

// ================= weight build =================
// wbuf bf16 elems:
// [0,40960)        ipw_ext [256][160]  (cols128-143 = ipw@loan1_w)
// [40960,57344)    opw [128][128]
// [57344,77824)    f1w_ext [128][160]  (cols128-143 = f1w@loan2_w)
// [77824,94208)    f2w [128][128]
// [94208,131072)   Wbig [2][144][128]  (dt_w folded xproj)
// f32 tail at wbuf+131072: bias_in[256], bias_f1[128]
__global__ __launch_bounds__(256) void k_cvt(
    const float* __restrict__ ipw, const float* __restrict__ opw,
    const float* __restrict__ f1w, const float* __restrict__ f2w,
    const float* __restrict__ xpw, const float* __restrict__ dtw,
    const float* __restrict__ l1w, const float* __restrict__ l1b,
    const float* __restrict__ l2w, const float* __restrict__ l2b,
    const float* __restrict__ fc1_b,
    __hip_bfloat16* __restrict__ wbuf)
{
  int i = blockIdx.x*256 + threadIdx.x;
  float* biasf = (float*)(wbuf + 131072);
  if (i >= 131072) {
    int j = i - 131072;
    if (j < 256) {            // bias_in
      float s = 0.f;
      for (int m=0;m<128;m++) s += ipw[j*128+m]*l1b[m];
      biasf[j] = s;
    } else if (j < 384) {     // bias_f1
      int n = j - 256;
      float s = fc1_b[n];
      for (int m=0;m<128;m++) s += f1w[n*128+m]*l2b[m];
      biasf[j] = s;
    }
    return;
  }
  float v;
  if (i < 40960) {
    int n = i/KEXT, col = i%KEXT;
    if (col < 128) v = ipw[n*128+col];
    else if (col < 144) { v = 0.f; int j = col-128;
      for (int m=0;m<128;m++) v += ipw[n*128+m]*l1w[m*16+j]; }
    else v = 0.f;
  } else if (i < 57344) v = opw[i-40960];
  else if (i < 77824) {
    int j = i-57344; int n = j/KEXT, col = j%KEXT;
    if (col < 128) v = f1w[n*128+col];
    else if (col < 144) { v = 0.f; int jj = col-128;
      for (int m=0;m<128;m++) v += f1w[n*128+m]*l2w[m*16+jj]; }
    else v = 0.f;
  } else if (i < 94208) v = f2w[i-77824];
  else {
    int j = i - 94208;
    int d = j / 18432;
    int rr = (j >> 7) % 144;
    int k = j & 127;
    if (rr < 128) {
      v = 0.f;
      #pragma unroll
      for (int r=0;r<8;r++) v += dtw[(d*128+rr)*8+r]*xpw[(d*10+r)*128+k];
    } else if (rr == 128) v = xpw[(d*10+8)*128+k];
    else if (rr == 129)  v = xpw[(d*10+9)*128+k];
    else v = 0.f;
  }
  wbuf[i] = __float2bfloat16(v);
}

// ================= prep: gather + LN -> A1[token][160] = [LN(x)|ss|0] =================
__global__ __launch_bounds__(256) void k_prep(
    const float* __restrict__ x, const float* __restrict__ xst,
    const int* __restrict__ curves, __hip_bfloat16* __restrict__ A1)
{
  int token = blockIdx.x*4 + (threadIdx.x>>6);
  int lane = threadIdx.x & 63;
  int b = token/60000, rem = token%60000, t = rem/10000, i = rem%10000;
  int c0 = curves[b*2*P_ + i];
  size_t src = ((size_t)(b*T_+t))*P_ + c0;
  float2 v = *reinterpret_cast<const float2*>(&x[src*128 + lane*2]);
  float s = v.x+v.y, q = v.x*v.x+v.y*v.y;
  #pragma unroll
  for (int d=1;d<64;d<<=1){ s += __shfl_xor(s,d); q += __shfl_xor(q,d); }
  float m = s*(1.f/128.f), var = q*(1.f/128.f)-m*m, rs = rsqrtf(var+1e-5f);
  __hip_bfloat162 o;
  o.x = __float2bfloat16((v.x-m)*rs);
  o.y = __float2bfloat16((v.y-m)*rs);
  size_t rowb = (size_t)token*KEXT;
  *reinterpret_cast<__hip_bfloat162*>(&A1[rowb + lane*2]) = o;
  if (lane < 16) A1[rowb + 128 + lane] = __float2bfloat16(xst[src*16+lane]);
  else if (lane < 32) A1[rowb + 128 + lane] = __float2bfloat16(0.f);
}

// ================= in_proj GEMM: Hbf[M,256] = A1[M,160] @ ipw_ext[256,160]^T + bias_in =====
__global__ __launch_bounds__(256) void k_gemm_in(
    const __hip_bfloat16* __restrict__ A, const __hip_bfloat16* __restrict__ Wb,
    const float* __restrict__ bias, __hip_bfloat16* __restrict__ C)
{
  __shared__ __hip_bfloat16 As[96][168];
  __shared__ __hip_bfloat16 Bs[128][168];
  const int tid = threadIdx.x;
  const size_t m0 = (size_t)blockIdx.x * 96;
  const int n0 = blockIdx.y * 128;
  #pragma unroll
  for (int p = 0; p < 8; ++p) {
    int ch = tid + p*256;
    if (ch < 1920) {
      int r = ch/20, c8 = ch%20;
      *reinterpret_cast<uint4*>(&As[r][c8*8]) =
        *reinterpret_cast<const uint4*>(&A[(m0 + r)*KEXT + c8*8]);
    }
  }
  #pragma unroll
  for (int p = 0; p < 10; ++p) {
    int ch = tid + p*256;
    int r = ch/20, c8 = ch%20;
    *reinterpret_cast<uint4*>(&Bs[r][c8*8]) =
      *reinterpret_cast<const uint4*>(&Wb[(size_t)(n0 + r)*KEXT + c8*8]);
  }
  __syncthreads();
  const int wave = tid >> 6, lane = tid & 63;
  const int rb = (wave >> 1) * 48, cb = (wave & 1) * 64;
  const int lrow = lane & 15, koff = (lane >> 4) * 8;
  f32x4 acc[3][4];
  #pragma unroll
  for (int i=0;i<3;i++) for (int j=0;j<4;j++) acc[i][j] = f32x4{0.f,0.f,0.f,0.f};
  #pragma unroll
  for (int kb = 0; kb < 5; ++kb) {
    short8 a[3], bf[4];
    #pragma unroll
    for (int i=0;i<3;i++) a[i] = *reinterpret_cast<const short8*>(&As[rb + i*16 + lrow][kb*32 + koff]);
    #pragma unroll
    for (int j=0;j<4;j++) bf[j] = *reinterpret_cast<const short8*>(&Bs[cb + j*16 + lrow][kb*32 + koff]);
    #pragma unroll
    for (int i=0;i<3;i++)
      #pragma unroll
      for (int j=0;j<4;j++)
        acc[i][j] = __builtin_amdgcn_mfma_f32_16x16x32_bf16(a[i], bf[j], acc[i][j], 0,0,0);
  }
  const int crow0 = (lane >> 4) * 4, ccol = lane & 15;
  #pragma unroll
  for (int i=0;i<3;i++) for (int j=0;j<4;j++){
    int n = n0 + cb + j*16 + ccol;
    float bv = bias[n];
    #pragma unroll
    for (int r=0;r<4;r++){
      size_t m = m0 + rb + i*16 + crow0 + r;
      C[m*256 + n] = __float2bfloat16(acc[i][j][r] + bv);
    }
  }
}

// ================= fused conv + xproj(MFMA) + scan =================
__global__ __launch_bounds__(128) void k_scan(
    const __hip_bfloat16* __restrict__ H,
    const float* __restrict__ conv_w, const float* __restrict__ conv_b,
    const __hip_bfloat16* __restrict__ Wbig,   // [2][144][128]
    const float* __restrict__ dt_b, const float* __restrict__ A_log,
    const float* __restrict__ Dp,
    __hip_bfloat16* __restrict__ Y)
{
  const int bid = blockIdx.x;
  const int dir = bid / NWIN;
  const int n   = bid % NWIN;
  const int c = threadIdx.x;
  const int b  = n / 2000;
  const int a  = (n / 1000) & 1;
  const int qw = n % 1000;
  __shared__ __hip_bfloat16 u_bf[32][136];
  __shared__ unsigned es[32][132];
  __shared__ float Bs_[32], Cs_[32];

  const int row0 = (b*T_ + a*G0_)*P_;
  float u[LWIN], z[LWIN];
  {
    float w0 = conv_w[(dir*DIMM + c)*3 + 0];
    float w1 = conv_w[(dir*DIMM + c)*3 + 1];
    float w2 = conv_w[(dir*DIMM + c)*3 + 2];
    float cbv = conv_b[dir*DIMM + c];
    float xm1 = 0.f, xm2 = 0.f;
    #pragma unroll
    for (int l=0;l<LWIN;l++){
      int pf = qw*G1_ + l%G1_;
      int p  = dir ? (P_-1-pf) : pf;
      size_t base = ((size_t)(row0 + (l/G1_)*P_ + p))*256;
      float xc = __bfloat162float(H[base + c]);
      z[l] = __bfloat162float(H[base + 128 + c]);
      u[l] = fsilu_(w0*xm2 + w1*xm1 + w2*xc + cbv);
      xm2 = xm1; xm1 = xc;
    }
  }
  #pragma unroll
  for (int l=0;l<LWIN;l++) u_bf[l][c] = __float2bfloat16(u[l]);
  u_bf[30][c] = __float2bfloat16(0.f);
  u_bf[31][c] = __float2bfloat16(0.f);
  __syncthreads();

  {
    const int wave = c >> 6, lane = c & 63;
    const int lrow = lane & 15, koff = (lane >> 4) * 8;
    const __hip_bfloat16* Wd = Wbig + (size_t)dir*144*128;
    f32x4 acc[9];
    #pragma unroll
    for (int t=0;t<9;t++) acc[t] = f32x4{0.f,0.f,0.f,0.f};
    #pragma unroll
    for (int kb=0; kb<4; ++kb){
      short8 av = *reinterpret_cast<const short8*>(&u_bf[wave*16 + lrow][kb*32 + koff]);
      #pragma unroll
      for (int t=0;t<9;t++){
        short8 bv = *reinterpret_cast<const short8*>(&Wd[(size_t)(t*16 + lrow)*128 + kb*32 + koff]);
        acc[t] = __builtin_amdgcn_mfma_f32_16x16x32_bf16(av, bv, acc[t], 0,0,0);
      }
    }
    const int l0 = wave*16 + (lane>>4)*4;
    #pragma unroll
    for (int t=0;t<8;t++){
      int j = t*16 + lrow;
      float dtbj = dt_b[dir*128 + j];
      float Avj = -__expf(A_log[dir*128 + j]);
      #pragma unroll
      for (int r=0;r<4;r++){
        float d = fsoftplus_(acc[t][r] + dtbj);
        float dA = __expf(d*Avj);
        es[l0+r][j] = (((unsigned)bf16bits_(dA))<<16) | (unsigned)bf16bits_(d);
      }
    }
    if (lrow < 2){
      #pragma unroll
      for (int r=0;r<4;r++){
        if (lrow==0) Bs_[l0+r] = acc[8][r];
        else         Cs_[l0+r] = acc[8][r];
      }
    }
  }
  __syncthreads();

  float Dv = Dp[dir*DIMM + c];
  float hst = 0.f;
  __hip_bfloat16* Yp = Y + ((size_t)dir*NWIN + n)*LWIN*DIMM;
  #pragma unroll
  for (int l=0;l<LWIN;l++){
    unsigned pk = es[l][c];
    float dA  = bits2f_((unsigned short)(pk>>16));
    float dlt = bits2f_((unsigned short)(pk & 0xffffu));
    float term = dlt*u[l]*Bs_[l];
    hst = fmaf(dA, hst, term);
    float y = fmaf(hst, Cs_[l], u[l]*Dv);
    y *= fsilu_(z[l]);
    Yp[l*DIMM + c] = __float2bfloat16(y);
  }
}

// ================= _wrev scramble index =================
__device__ __forceinline__ int win_index(int t, int p){
  int G  = t*P_ + p;
  int d3 = G / 6000;
  int r  = G % 6000;
  int d1 = r / 6;
  int r2 = r % 6;
  int d4 = r2 >> 1;
  int d2 = r2 & 1;
  int F  = d1*60 + d2*30 + d3*3 + d4;
  int a  = F / 30000;
  int F2 = F % 30000;
  int qw = F2 / 30;
  int l  = F2 % 30;
  return (a*1000 + qw)*LWIN + l;
}

// ================= out_proj GEMM with fused gather/average A-load, bf16 out ======
__global__ __launch_bounds__(256) void k_gemm_out(
    const __hip_bfloat16* __restrict__ Y, const __hip_bfloat16* __restrict__ Wb,
    __hip_bfloat16* __restrict__ yproj)
{
  __shared__ __hip_bfloat16 As[96][136];
  __shared__ __hip_bfloat16 Bs[128][136];
  const int tid = threadIdx.x;
  const size_t m0 = (size_t)blockIdx.x * 96;
  const __hip_bfloat16* Yb = Y + (size_t)NWIN*LWIN*DIMM;
  #pragma unroll
  for (int p = 0; p < 6; ++p) {
    int ch = tid + p*256; int r = ch >> 4, c16 = ch & 15;
    int token = (int)m0 + r;
    int b = token/60000, rem = token%60000, t = rem/10000, pp = rem%10000;
    size_t bbase = (size_t)b*60000;
    int wf = win_index(t, pp), wb = win_index(t, P_-1-pp);
    uint4 f = *reinterpret_cast<const uint4*>(&Y [(bbase+wf)*128 + c16*8]);
    uint4 g = *reinterpret_cast<const uint4*>(&Yb[(bbase+wb)*128 + c16*8]);
    unsigned o[4];
    const unsigned* fu = reinterpret_cast<const unsigned*>(&f);
    const unsigned* gu = reinterpret_cast<const unsigned*>(&g);
    #pragma unroll
    for (int k=0;k<4;k++){
      float flo = bits2f_((unsigned short)(fu[k] & 0xffffu));
      float fhi = bits2f_((unsigned short)(fu[k] >> 16));
      float glo = bits2f_((unsigned short)(gu[k] & 0xffffu));
      float ghi = bits2f_((unsigned short)(gu[k] >> 16));
      o[k] = (((unsigned)bf16bits_(0.5f*(fhi+ghi)))<<16) | (unsigned)bf16bits_(0.5f*(flo+glo));
    }
    *reinterpret_cast<uint4*>(&As[r][c16*8]) = *reinterpret_cast<uint4*>(o);
  }
  #pragma unroll
  for (int p = 0; p < 8; ++p) {
    int ch = tid + p*256; int r = ch >> 4, c16 = ch & 15;
    *reinterpret_cast<uint4*>(&Bs[r][c16*8]) =
      *reinterpret_cast<const uint4*>(&Wb[(size_t)r*128 + c16*8]);
  }
  __syncthreads();
  const int wave = tid >> 6, lane = tid & 63;
  const int rb = (wave >> 1) * 48, cb = (wave & 1) * 64;
  const int lrow = lane & 15, koff = (lane >> 4) * 8;
  f32x4 acc[3][4];
  #pragma unroll
  for (int i=0;i<3;i++) for (int j=0;j<4;j++) acc[i][j] = f32x4{0.f,0.f,0.f,0.f};
  #pragma unroll
  for (int kb = 0; kb < 4; ++kb) {
    short8 a[3], bf[4];
    #pragma unroll
    for (int i=0;i<3;i++) a[i] = *reinterpret_cast<const short8*>(&As[rb + i*16 + lrow][kb*32 + koff]);
    #pragma unroll
    for (int j=0;j<4;j++) bf[j] = *reinterpret_cast<const short8*>(&Bs[cb + j*16 + lrow][kb*32 + koff]);
    #pragma unroll
    for (int i=0;i<3;i++)
      #pragma unroll
      for (int j=0;j<4;j++)
        acc[i][j] = __builtin_amdgcn_mfma_f32_16x16x32_bf16(a[i], bf[j], acc[i][j], 0,0,0);
  }
  const int crow0 = (lane >> 4) * 4, ccol = lane & 15;
  #pragma unroll
  for (int i=0;i<3;i++) for (int j=0;j<4;j++){
    int nn = cb + j*16 + ccol;
    #pragma unroll
    for (int r=0;r<4;r++){
      size_t m = m0 + rb + i*16 + crow0 + r;
      yproj[m*128 + nn] = __float2bfloat16(acc[i][j][r]);
    }
  }
}

// ================= mid: x1 = xs + yproj (f32) ; A2 = [LN(x1)|ss|0] =================
__global__ __launch_bounds__(256) void k_mid(
    const float* __restrict__ x, const float* __restrict__ xst,
    const int* __restrict__ curves, const __hip_bfloat16* __restrict__ yproj,
    float* __restrict__ x1, __hip_bfloat16* __restrict__ A2)
{
  int token = blockIdx.x*4 + (threadIdx.x>>6);
  int lane = threadIdx.x & 63;
  int b = token/60000, rem = token%60000, t = rem/10000, i = rem%10000;
  int c0 = curves[b*2*P_ + i];
  size_t src = ((size_t)(b*T_+t))*P_ + c0;
  float2 v = *reinterpret_cast<const float2*>(&x[src*128 + lane*2]);
  __hip_bfloat162 yp = *reinterpret_cast<const __hip_bfloat162*>(&yproj[(size_t)token*128 + lane*2]);
  v.x += __bfloat162float(yp.x); v.y += __bfloat162float(yp.y);
  *reinterpret_cast<float2*>(&x1[(size_t)token*128 + lane*2]) = v;
  float s = v.x+v.y, q = v.x*v.x+v.y*v.y;
  #pragma unroll
  for (int d=1;d<64;d<<=1){ s += __shfl_xor(s,d); q += __shfl_xor(q,d); }
  float m = s*(1.f/128.f), var = q*(1.f/128.f)-m*m, rs = rsqrtf(var+1e-5f);
  __hip_bfloat162 o;
  o.x = __float2bfloat16((v.x-m)*rs);
  o.y = __float2bfloat16((v.y-m)*rs);
  size_t rowb = (size_t)token*KEXT;
  *reinterpret_cast<__hip_bfloat162*>(&A2[rowb + lane*2]) = o;
  if (lane < 16) A2[rowb + 128 + lane] = __float2bfloat16(xst[src*16+lane]);
  else if (lane < 32) A2[rowb + 128 + lane] = __float2bfloat16(0.f);
}

// ================= fused MLP: x2 = bf16(x1 + fc2(gelu(fc1e(A2)))) =================
__global__ __launch_bounds__(256) void k_gemm_mlp(
    const __hip_bfloat16* __restrict__ A, const __hip_bfloat16* __restrict__ W1e,
    const __hip_bfloat16* __restrict__ W2,
    const float* __restrict__ b1e, const float* __restrict__ b2,
    const float* __restrict__ x1, __hip_bfloat16* __restrict__ x2)
{
  __shared__ __hip_bfloat16 As[96][168];
  __shared__ __hip_bfloat16 Bs[128][168];
  const int tid = threadIdx.x;
  const size_t m0 = (size_t)blockIdx.x * 96;
  #pragma unroll
  for (int p = 0; p < 8; ++p) {
    int ch = tid + p*256;
    if (ch < 1920) {
      int r = ch/20, c8 = ch%20;
      *reinterpret_cast<uint4*>(&As[r][c8*8]) =
        *reinterpret_cast<const uint4*>(&A[(m0 + r)*KEXT + c8*8]);
    }
  }
  #pragma unroll
  for (int p = 0; p < 10; ++p) {
    int ch = tid + p*256;
    int r = ch/20, c8 = ch%20;
    *reinterpret_cast<uint4*>(&Bs[r][c8*8]) =
      *reinterpret_cast<const uint4*>(&W1e[(size_t)r*KEXT + c8*8]);
  }
  __syncthreads();
  const int wave = tid >> 6, lane = tid & 63;
  const int rb = (wave >> 1) * 48, cb = (wave & 1) * 64;
  const int lrow = lane & 15, koff = (lane >> 4) * 8;
  const int crow0 = (lane >> 4) * 4, ccol = lane & 15;
  f32x4 acc[3][4];
  #pragma unroll
  for (int i=0;i<3;i++) for (int j=0;j<4;j++) acc[i][j] = f32x4{0.f,0.f,0.f,0.f};
  #pragma unroll
  for (int kb = 0; kb < 5; ++kb) {
    short8 a[3], bf[4];
    #pragma unroll
    for (int i=0;i<3;i++) a[i] = *reinterpret_cast<const short8*>(&As[rb + i*16 + lrow][kb*32 + koff]);
    #pragma unroll
    for (int j=0;j<4;j++) bf[j] = *reinterpret_cast<const short8*>(&Bs[cb + j*16 + lrow][kb*32 + koff]);
    #pragma unroll
    for (int i=0;i<3;i++)
      #pragma unroll
      for (int j=0;j<4;j++)
        acc[i][j] = __builtin_amdgcn_mfma_f32_16x16x32_bf16(a[i], bf[j], acc[i][j], 0,0,0);
  }
  __syncthreads();
  #pragma unroll
  for (int i=0;i<3;i++) for (int j=0;j<4;j++){
    int nn = cb + j*16 + ccol;
    float bv = b1e[nn];
    #pragma unroll
    for (int r=0;r<4;r++){
      int row = rb + i*16 + crow0 + r;
      As[row][nn] = __float2bfloat16(geluf_(acc[i][j][r] + bv));
    }
  }
  #pragma unroll
  for (int p = 0; p < 8; ++p) {
    int ch = tid + p*256; int r = ch >> 4, c16 = ch & 15;
    *reinterpret_cast<uint4*>(&Bs[r][c16*8]) =
      *reinterpret_cast<const uint4*>(&W2[(size_t)r*128 + c16*8]);
  }
  __syncthreads();
  #pragma unroll
  for (int i=0;i<3;i++) for (int j=0;j<4;j++) acc[i][j] = f32x4{0.f,0.f,0.f,0.f};
  #pragma unroll
  for (int kb = 0; kb < 4; ++kb) {
    short8 a[3], bf[4];
    #pragma unroll
    for (int i=0;i<3;i++) a[i] = *reinterpret_cast<const short8*>(&As[rb + i*16 + lrow][kb*32 + koff]);
    #pragma unroll
    for (int j=0;j<4;j++) bf[j] = *reinterpret_cast<const short8*>(&Bs[cb + j*16 + lrow][kb*32 + koff]);
    #pragma unroll
    for (int i=0;i<3;i++)
      #pragma unroll
      for (int j=0;j<4;j++)
        acc[i][j] = __builtin_amdgcn_mfma_f32_16x16x32_bf16(a[i], bf[j], acc[i][j], 0,0,0);
  }
  #pragma unroll
  for (int i=0;i<3;i++) for (int j=0;j<4;j++){
    int nn = cb + j*16 + ccol;
    float bv = b2[nn];
    #pragma unroll
    for (int r=0;r<4;r++){
      size_t m = m0 + rb + i*16 + crow0 + r;
      x2[m*128 + nn] = __float2bfloat16(acc[i][j][r] + bv + x1[m*128 + nn]);
    }
  }
}

// ================= final: gather x2 by c1 -> f32 out =================
__global__ __launch_bounds__(256) void k_final(
    const __hip_bfloat16* __restrict__ x2, const int* __restrict__ curves,
    float* __restrict__ out)
{
  int token = blockIdx.x*4 + (threadIdx.x>>6);
  int lane = threadIdx.x & 63;
  int b = token/60000, rem = token%60000, t = rem/10000, i = rem%10000;
  int c1 = curves[(b*2+1)*P_ + i];
  size_t src = ((size_t)(b*T_+t))*P_ + c1;
  __hip_bfloat162 v = *reinterpret_cast<const __hip_bfloat162*>(&x2[src*128 + lane*2]);
  float2 o; o.x = __bfloat162float(v.x); o.y = __bfloat162float(v.y);
  *reinterpret_cast<float2*>(&out[(size_t)token*128 + lane*2]) = o;
}

extern "C" void kernel_launch(void* const* d_in, const int* in_sizes, int n_in,
                              void* d_out, int out_size, void* d_ws, size_t ws_size,
                              hipStream_t stream) {
  const float* x        = (const float*)d_in[0];
  const float* xst      = (const float*)d_in[1];
  const int*   curves   = (const int*)  d_in[2];
  const float* loan1_w  = (const float*)d_in[3];
  const float* loan1_b  = (const float*)d_in[4];
  const float* loan2_w  = (const float*)d_in[5];
  const float* loan2_b  = (const float*)d_in[6];
  const float* in_proj_w  = (const float*)d_in[7];
  const float* out_proj_w = (const float*)d_in[8];
  const float* conv_w   = (const float*)d_in[9];
  const float* conv_b   = (const float*)d_in[10];
  const float* xproj_w  = (const float*)d_in[11];
  const float* dt_w     = (const float*)d_in[12];
  const float* dt_b     = (const float*)d_in[13];
  const float* A_log    = (const float*)d_in[14];
  const float* Dvec     = (const float*)d_in[15];
  const float* fc1_w    = (const float*)d_in[16];
  const float* fc1_b    = (const float*)d_in[17];
  const float* fc2_w    = (const float*)d_in[18];
  const float* fc2_b    = (const float*)d_in[19];
  float* out = (float*)d_out;

  char* ws = (char*)d_ws;
  // R0 [0, 61.44M):   A1(38.4M) -> Y(61.44M) -> x1(61.44M f32)
  // [61.44M, 92.16M): Hbf part1... Hbf occupies [61.44M,122.88M); after scan:
  //   yproj bf16 at 61.44M..92.16M ; A2 at 92.16M..130.56M ; x2 at 130.56M..161.28M
  // weights at 161.28M
  __hip_bfloat16* A1   = (__hip_bfloat16*)(ws + 0);
  __hip_bfloat16* Ybuf = (__hip_bfloat16*)(ws + 0);
  float*          x1   = (float*)(ws + 0);
  __hip_bfloat16* Hbf  = (__hip_bfloat16*)(ws + 61440000);
  __hip_bfloat16* yproj= (__hip_bfloat16*)(ws + 61440000);
  __hip_bfloat16* A2   = (__hip_bfloat16*)(ws + 92160000);
  __hip_bfloat16* x2   = (__hip_bfloat16*)(ws + 130560000);
  __hip_bfloat16* wbuf = (__hip_bfloat16*)(ws + 161280000);
  __hip_bfloat16* ipw_e  = wbuf;
  __hip_bfloat16* opw_bf = wbuf + 40960;
  __hip_bfloat16* f1w_e  = wbuf + 57344;
  __hip_bfloat16* f2w_bf = wbuf + 77824;
  __hip_bfloat16* Wbig   = wbuf + 94208;
  float* biasf = (float*)(wbuf + 131072);
  float* bias_in = biasf;
  float* bias_f1 = biasf + 256;

  k_cvt<<<514, 256, 0, stream>>>(in_proj_w, out_proj_w, fc1_w, fc2_w, xproj_w, dt_w,
                                 loan1_w, loan1_b, loan2_w, loan2_b, fc1_b, wbuf);
  k_prep<<<NTOK/4, 256, 0, stream>>>(x, xst, curves, A1);

  dim3 g1(NTOK/96, 2);
  k_gemm_in<<<g1, 256, 0, stream>>>(A1, ipw_e, bias_in, Hbf);

  k_scan<<<2*NWIN, 128, 0, stream>>>(Hbf, conv_w, conv_b, Wbig, dt_b, A_log, Dvec, Ybuf);

  k_gemm_out<<<NTOK/96, 256, 0, stream>>>(Ybuf, opw_bf, yproj);

  k_mid<<<NTOK/4, 256, 0, stream>>>(x, xst, curves, yproj, x1, A2);

  k_gemm_mlp<<<NTOK/96, 256, 0, stream>>>(A2, f1w_e, f2w_bf, bias_f1, fc2_b, x1, x2);

  k_final<<<NTOK/4, 256, 0, stream>>>(x2, curves, out);
}